// Round 14
// baseline (690.336 us; speedup 1.0000x reference)
//
#include <hip/hip_runtime.h>
#include <hip/hip_bf16.h>
#include <math.h>

namespace {

typedef short  short8 __attribute__((ext_vector_type(8)));
typedef float  f32x4  __attribute__((ext_vector_type(4)));

constexpr int BB = 2, CC = 64, HH = 256, WW = 512, OO = 64, KK = 9;
constexpr int PXB  = 128;   // pixels per block
constexpr int NGRP = 32;    // channel pairs
constexpr int CHW_F = 5 * WW;          // 5-row window h-2..h+2 (|py-h|<1.415 proven)
constexpr int BUF_F = 2 * CHW_F;       // 2 channels per buffer
constexpr int SSTR  = 42;              // Sb row stride (21 dwords, odd -> b128 conflict-free)

__device__ __forceinline__ ushort f2bf(float f) {   // HW RNE via v_cvt_pk_bf16_f32
  __hip_bfloat16 h = __float2bfloat16(f);
  return __builtin_bit_cast(unsigned short, h);
}

__global__ __launch_bounds__(256, 3) void equiconv_mfma(
    const float* __restrict__ x, const float* __restrict__ wgt,
    const float* __restrict__ bias, float* __restrict__ out)
{
  __shared__ __align__(16) float  lbx[2][BUF_F];    // 40 KB: double-buffered x windows
  __shared__ __align__(16) ushort Sb[PXB * SSTR];   // 10.75 KB

  const int tid  = threadIdx.x;
  const int wid  = tid >> 6, lane = tid & 63;
  const int p    = tid & (PXB - 1);
  const int cc   = tid >> 7;              // channel parity for the gather
  const int w    = blockIdx.x * PXB + p;
  const int h    = blockIdx.y;
  const int b    = blockIdx.z;

  // ---- geometry: verbatim bit-faithful f32 chain (PASSED r3/r4/r10-r12) ----
  int   jx[KK][4];
  float cw[KK][4];
  {
#pragma clang fp contract(off)
    const float TWO_PI_F = (float)(2.0 * M_PI);
    const float PI_F     = (float)M_PI;
    const float XS       = (float)(512.0 / (2.0 * M_PI));
    const float YS       = (float)(256.0 / M_PI);

    const float uf = (float)w, vf = (float)h;
    const float phi   = ((uf - 256.0f) / 512.0f) * TWO_PI_F;
    const float theta = ((-(vf - 128.0f)) / 256.0f) * PI_F;

    const float sp = (float)sin((double)phi);
    const float cp = (float)cos((double)phi);
    const float st = (float)sin((double)theta);
    const float ct = (float)cos((double)theta);

    const float R00 = cp;        const float R01 = sp * st;  const float R02 = sp * ct;
    /* R10 = 0 */                const float R11 = ct;       const float R12 = -st;
    const float R20 = -sp;       const float R21 = cp * st;  const float R22 = cp * ct;

    const double focal_d = 1.5 / tan(0.5 * (3.0 * (2.0 * M_PI / 512.0)));
    const float  focal_f = (float)focal_d;

    for (int k = 0; k < KK; ++k) {
      const float wgk = (float)(k % 3) + 0.5f - 1.5f;
      const float hgk = (float)(k / 3) + 0.5f - 1.5f;

      float rx0 = wgk / focal_f, ry0 = hgk / focal_f, rz0 = 1.0f;
      const float nrm = sqrtf(((rx0 * rx0) + (ry0 * ry0)) + (rz0 * rz0));
      rx0 = rx0 / nrm; ry0 = ry0 / nrm; rz0 = rz0 / nrm;

      const float r0 = ((R00 * rx0) + (R01 * ry0)) + (R02 * rz0);
      const float r1 =               ((R11 * ry0)) + (R12 * rz0);
      const float r2 = ((R20 * rx0) + (R21 * ry0)) + (R22 * rz0);

      const float phi2 = (float)atan2((double)r0, (double)r2);
      float r1c = r1;
      if (r1c >  1.0f) r1c =  1.0f;
      if (r1c < -1.0f) r1c = -1.0f;
      const float th2 = (float)asin((double)r1c);

      const float xx = (XS * phi2) + 256.0f;
      const float yy = (YS * th2)  + 128.0f;

      const float Ax = (float)(w + (k % 3) - 1);
      const float Ay = (float)(h + (k / 3) - 1);
      const float px = Ax + (xx - Ax);
      const float py = Ay + (yy - Ay);

      const float x0f = floorf(px), y0f = floorf(py);
      const float wx1 = px - x0f,   wy1 = py - y0f;
      const int ix0 = (int)x0f, iy0 = (int)y0f;
      const int ix1 = ix0 + 1,  iy1 = iy0 + 1;
      const bool vx0 = (ix0 >= 0) && (ix0 < WW);
      const bool vx1 = (ix1 >= 0) && (ix1 < WW);
      const bool vy0 = (iy0 >= 0) && (iy0 < HH);
      const bool vy1 = (iy1 >= 0) && (iy1 < HH);
      const int cx0 = min(max(ix0, 0), WW - 1);
      const int cx1 = min(max(ix1, 0), WW - 1);
      const int cy0 = min(max(iy0, 0), HH - 1);
      const int cy1 = min(max(iy1, 0), HH - 1);
      // 5-row window: LDS row j holds plane row clamp(h-2+j); j0,j1 in [0,4]
      // (|py-h| <= 256/pi * atan(sqrt(2)/focal) = 1.4147 => iy1 <= h+2).
      const int j0 = cy0 - h + 2;
      const int j1 = cy1 - h + 2;
      jx[k][0] = j0 * WW + cx0;
      jx[k][1] = j0 * WW + cx1;
      jx[k][2] = j1 * WW + cx0;
      jx[k][3] = j1 * WW + cx1;
      const float wy0f = 1.0f - wy1, wx0f = 1.0f - wx1;
      cw[k][0] = (wy0f * wx0f) * ((vy0 && vx0) ? 1.0f : 0.0f);
      cw[k][1] = (wy0f * wx1)  * ((vy0 && vx1) ? 1.0f : 0.0f);
      cw[k][2] = (wy1 * wx0f)  * ((vy1 && vx0) ? 1.0f : 0.0f);
      cw[k][3] = (wy1 * wx1)   * ((vy1 && vx1) ? 1.0f : 0.0f);
    }
  }

  // zero Sb once (zero k-slots stay zero forever; A-side zeros also kill them)
  {
    uint* S32 = (uint*)Sb;                      // 128*21 = 2688 u32
#pragma unroll
    for (int i = 0; i < 11; ++i) {
      const int idx = tid + 256 * i;
      if (idx < (PXB * SSTR) / 2) S32[idx] = 0u;
    }
  }

  // stage 2 channels of group g2 into buf bi: 20 x 1KB chunks, 5 per wave
  auto stage = [&](int bi, int g2) {
#pragma unroll
    for (int i = 0; i < 5; ++i) {
      const int ci  = wid * 5 + i;              // 0..19, wave-uniform
      const int ccs = ci / 10, r2 = ci % 10, j = r2 >> 1, half = r2 & 1;
      const int srow = min(max(h - 2 + j, 0), HH - 1);
      const int ch   = g2 * 2 + ccs;
      const float* src = x + (((size_t)b * CC + ch) * HH + srow) * WW + half * 256 + lane * 4;
      __builtin_amdgcn_global_load_lds(
          (const __attribute__((address_space(1))) void*)src,
          (__attribute__((address_space(3))) void*)&lbx[bi][ccs * CHW_F + j * 512 + half * 256],
          16, 0, 0);
    }
  };

  f32x4 acc[4][2];
#pragma unroll
  for (int ot = 0; ot < 4; ++ot)
#pragma unroll
    for (int pt = 0; pt < 2; ++pt) acc[ot][pt] = (f32x4){0.f, 0.f, 0.f, 0.f};

  stage(0, 0);   // prologue prefetch

#pragma unroll 1
  for (int g = 0; g < NGRP; ++g) {
    const int bi = g & 1;

    // A fragments from L2-resident wgt (NOT d_ws: r13 showed d_ws is uncached).
    // Pinned BEFORE stage(g+1) so vmcnt(5) always drains them (oldest-first).
    short8 A[4];
    {
      const int lg = lane >> 4;
      const int c  = g * 2 + (lg >> 1);
#pragma unroll
      for (int ot = 0; ot < 4; ++ot) {
        const int o = ot * 16 + (lane & 15);
        const float* wp9 = wgt + ((size_t)o * 64 + c) * 9;
        short8 a;
        if ((lg & 1) == 0) {
#pragma unroll
          for (int j = 0; j < 8; ++j) a[j] = (short)f2bf(wp9[j]);
        } else {
          a = (short8){0, 0, 0, 0, 0, 0, 0, 0};
          a[0] = (short)f2bf(wp9[8]);
        }
        A[ot] = a;
      }
    }
    __builtin_amdgcn_sched_barrier(0);          // pin A-loads before stage(g+1)

    if (g < NGRP - 1) {
      stage(bi ^ 1, g + 1);                     // prefetch next group's windows
      asm volatile("s_waitcnt vmcnt(5)" ::: "memory");   // drain stage(g)+A; keep stage(g+1)
    } else {
      asm volatile("s_waitcnt vmcnt(0)" ::: "memory");
    }
    __builtin_amdgcn_sched_barrier(0);
    __builtin_amdgcn_s_barrier();               // BARRIER A: lbx[bi] visible everywhere
    __builtin_amdgcn_sched_barrier(0);

    // ---- gather channel 2g+cc for pixel p (verbatim r10-r12 data path) ----
    {
      const float* Lc = &lbx[bi][cc * CHW_F];
      float s[KK];
#pragma unroll
      for (int k = 0; k < KK; ++k) {
        s[k] = fmaf(cw[k][3], Lc[jx[k][3]],
               fmaf(cw[k][2], Lc[jx[k][2]],
               fmaf(cw[k][1], Lc[jx[k][1]],
                    cw[k][0] * Lc[jx[k][0]])));
      }
      const uint b0 = f2bf(s[0]), b1 = f2bf(s[1]), b2 = f2bf(s[2]);
      const uint b3 = f2bf(s[3]), b4 = f2bf(s[4]), b5 = f2bf(s[5]);
      const uint b6 = f2bf(s[6]), b7 = f2bf(s[7]), b8 = f2bf(s[8]);
      uint2* Sr = (uint2*)(Sb + p * SSTR + cc * 16);
      Sr[0] = make_uint2(b0 | (b1 << 16), b2 | (b3 << 16));
      Sr[1] = make_uint2(b4 | (b5 << 16), b6 | (b7 << 16));
      Sb[p * SSTR + cc * 16 + 8] = (ushort)b8;
    }

    asm volatile("s_waitcnt lgkmcnt(0)" ::: "memory");
    __builtin_amdgcn_sched_barrier(0);
    __builtin_amdgcn_s_barrier();               // BARRIER B: Sb(g) complete
    __builtin_amdgcn_sched_barrier(0);

    // ---- B fragments + MFMA, scheduler-pinned (rule #18, r11/r12-proven) ----
    // Sb single-buffer safety: Bfr ds_reads drain at lgkmcnt(0) below, before
    // this wave reaches BARRIER A(g+1); Sb(g+1) writes happen only after it.
    // lbx reads drain before BARRIER B(g); next writes to this buf are
    // stage(g+2), issued after BARRIER B(g).
    short8 Bfr[2];
#pragma unroll
    for (int pt = 0; pt < 2; ++pt) {
      const int prow = wid * 32 + pt * 16 + (lane & 15);
      Bfr[pt] = *(const short8*)(Sb + prow * SSTR + ((lane >> 4) & 3) * 8);
    }
    asm volatile("s_waitcnt lgkmcnt(0)" ::: "memory");
    __builtin_amdgcn_sched_barrier(0);          // MFMA must not hoist above the wait
#pragma unroll
    for (int ot = 0; ot < 4; ++ot)
#pragma unroll
      for (int pt = 0; pt < 2; ++pt)
        acc[ot][pt] = __builtin_amdgcn_mfma_f32_16x16x32_bf16(A[ot], Bfr[pt], acc[ot][pt], 0, 0, 0);
    __builtin_amdgcn_sched_barrier(0);          // nothing sinks/hoists across the cluster
  }

  // ---- epilogue: D row=(lane>>4)*4+r, col=lane&15 (m89 layout, proven) ----
#pragma unroll
  for (int ot = 0; ot < 4; ++ot) {
    const int o = ot * 16 + ((lane >> 4) & 3) * 4;
#pragma unroll
    for (int pt = 0; pt < 2; ++pt) {
      const int wcol = blockIdx.x * PXB + wid * 32 + pt * 16 + (lane & 15);
#pragma unroll
      for (int r = 0; r < 4; ++r)
        out[(((size_t)b * OO + (o + r)) * HH + h) * WW + wcol] = acc[ot][pt][r] + bias[o + r];
    }
  }
}

} // namespace

extern "C" void kernel_launch(void* const* d_in, const int* in_sizes, int n_in,
                              void* d_out, int out_size, void* d_ws, size_t ws_size,
                              hipStream_t stream) {
  const float* x      = (const float*)d_in[0];
  const float* weight = (const float*)d_in[1];
  const float* bias   = (const float*)d_in[2];
  float* out          = (float*)d_out;

  dim3 grid(WW / PXB, HH, BB);                  // 4 x 256 x 2
  hipLaunchKernelGGL(equiconv_mfma, grid, dim3(256), 0, stream,
                     x, weight, bias, out);
}

// Round 15
// 372.282 us; speedup vs baseline: 1.8543x; 1.8543x over previous
//
#include <hip/hip_runtime.h>
#include <math.h>

namespace {

typedef short  short8 __attribute__((ext_vector_type(8)));
typedef float  f32x4  __attribute__((ext_vector_type(4)));

constexpr int BB = 2, CC = 64, HH = 256, WW = 512, OO = 64, KK = 9;
constexpr int PXB  = 128;   // pixels per block
constexpr int NGRP = 32;    // channel pairs
constexpr int CHW_F = 6 * WW;          // 6-row window (r12-proven), 3072 floats
constexpr int BUF_F = 2 * CHW_F;       // 2 channels per buffer
constexpr int SSTR  = 42;              // Sb row stride in ushorts

__device__ __forceinline__ uint rne_bf16(float f) {
  uint u = __float_as_uint(f);
  return (u + 0x7fffu + ((u >> 16) & 1u)) >> 16;   // RNE, finite inputs
}

__global__ __launch_bounds__(256, 2) void equiconv_mfma(
    const float* __restrict__ x, const float* __restrict__ wgt,
    const float* __restrict__ bias, float* __restrict__ out)
{
  __shared__ __align__(16) float  lbx[2][BUF_F];    // 48 KB: double-buffered x windows
  __shared__ __align__(16) ushort Sb[PXB * SSTR];   // 10.5 KB, wave-local regions

  const int tid  = threadIdx.x;
  const int wid  = tid >> 6, lane = tid & 63;
  // WAVE-LOCAL pixel assignment: wave wid gathers for ITS OWN 32 MFMA pixels.
  // lane -> pixel p = wid*32 + (lane&31), channel parity cc = lane>>5.
  // Every Sb row this wave reads (wid*32+pt*16+(lane&15)) is written by this
  // wave only -> the Sb producer/consumer edge is wave-internal -> barrier B
  // becomes a wave-local lgkmcnt(0). Sample math identical to r12 (bit-exact).
  const int p    = wid * 32 + (lane & 31);
  const int cc   = lane >> 5;
  const int w    = blockIdx.x * PXB + p;
  const int h    = blockIdx.y;
  const int b    = blockIdx.z;

  // ---- geometry: verbatim bit-faithful f32 chain (PASSED r3/r4/r10-r12) ----
  int   jx[KK][4];
  float cw[KK][4];
  {
#pragma clang fp contract(off)
    const float TWO_PI_F = (float)(2.0 * M_PI);
    const float PI_F     = (float)M_PI;
    const float XS       = (float)(512.0 / (2.0 * M_PI));
    const float YS       = (float)(256.0 / M_PI);

    const float uf = (float)w, vf = (float)h;
    const float phi   = ((uf - 256.0f) / 512.0f) * TWO_PI_F;
    const float theta = ((-(vf - 128.0f)) / 256.0f) * PI_F;

    const float sp = (float)sin((double)phi);
    const float cp = (float)cos((double)phi);
    const float st = (float)sin((double)theta);
    const float ct = (float)cos((double)theta);

    const float R00 = cp;        const float R01 = sp * st;  const float R02 = sp * ct;
    /* R10 = 0 */                const float R11 = ct;       const float R12 = -st;
    const float R20 = -sp;       const float R21 = cp * st;  const float R22 = cp * ct;

    const double focal_d = 1.5 / tan(0.5 * (3.0 * (2.0 * M_PI / 512.0)));
    const float  focal_f = (float)focal_d;

    for (int k = 0; k < KK; ++k) {
      const float wgk = (float)(k % 3) + 0.5f - 1.5f;
      const float hgk = (float)(k / 3) + 0.5f - 1.5f;

      float rx0 = wgk / focal_f, ry0 = hgk / focal_f, rz0 = 1.0f;
      const float nrm = sqrtf(((rx0 * rx0) + (ry0 * ry0)) + (rz0 * rz0));
      rx0 = rx0 / nrm; ry0 = ry0 / nrm; rz0 = rz0 / nrm;

      const float r0 = ((R00 * rx0) + (R01 * ry0)) + (R02 * rz0);
      const float r1 =               ((R11 * ry0)) + (R12 * rz0);
      const float r2 = ((R20 * rx0) + (R21 * ry0)) + (R22 * rz0);

      const float phi2 = (float)atan2((double)r0, (double)r2);
      float r1c = r1;
      if (r1c >  1.0f) r1c =  1.0f;
      if (r1c < -1.0f) r1c = -1.0f;
      const float th2 = (float)asin((double)r1c);

      const float xx = (XS * phi2) + 256.0f;
      const float yy = (YS * th2)  + 128.0f;

      const float Ax = (float)(w + (k % 3) - 1);
      const float Ay = (float)(h + (k / 3) - 1);
      const float px = Ax + (xx - Ax);
      const float py = Ay + (yy - Ay);

      const float x0f = floorf(px), y0f = floorf(py);
      const float wx1 = px - x0f,   wy1 = py - y0f;
      const int ix0 = (int)x0f, iy0 = (int)y0f;
      const int ix1 = ix0 + 1,  iy1 = iy0 + 1;
      const bool vx0 = (ix0 >= 0) && (ix0 < WW);
      const bool vx1 = (ix1 >= 0) && (ix1 < WW);
      const bool vy0 = (iy0 >= 0) && (iy0 < HH);
      const bool vy1 = (iy1 >= 0) && (iy1 < HH);
      const int cx0 = min(max(ix0, 0), WW - 1);
      const int cx1 = min(max(ix1, 0), WW - 1);
      const int cy0 = min(max(iy0, 0), HH - 1);
      const int cy1 = min(max(iy1, 0), HH - 1);
      const int j0 = cy0 - h + 2;   // LDS row j holds plane row clamp(h-2+j)
      const int j1 = cy1 - h + 2;
      jx[k][0] = j0 * WW + cx0;
      jx[k][1] = j0 * WW + cx1;
      jx[k][2] = j1 * WW + cx0;
      jx[k][3] = j1 * WW + cx1;
      const float wy0f = 1.0f - wy1, wx0f = 1.0f - wx1;
      cw[k][0] = (wy0f * wx0f) * ((vy0 && vx0) ? 1.0f : 0.0f);
      cw[k][1] = (wy0f * wx1)  * ((vy0 && vx1) ? 1.0f : 0.0f);
      cw[k][2] = (wy1 * wx0f)  * ((vy1 && vx0) ? 1.0f : 0.0f);
      cw[k][3] = (wy1 * wx1)   * ((vy1 && vx1) ? 1.0f : 0.0f);
    }
  }

  // zero Sb once (zero k-slots stay zero forever; A-side zeros also kill them)
  {
    uint* S32 = (uint*)Sb;                      // 128*21 = 2688 u32
#pragma unroll
    for (int i = 0; i < 11; ++i) {
      const int idx = tid + 256 * i;
      if (idx < (PXB * SSTR) / 2) S32[idx] = 0u;
    }
  }

  // stage 2 channels of group g2 into buf bi: 24 x 1KB chunks, 6 per wave
  auto stage = [&](int bi, int g2) {
#pragma unroll
    for (int i = 0; i < 6; ++i) {
      const int ci  = wid * 6 + i;              // 0..23, wave-uniform
      const int ccs = ci / 12, r2 = ci % 12, j = r2 >> 1, half = r2 & 1;
      const int srow = min(max(h - 2 + j, 0), HH - 1);
      const int ch   = g2 * 2 + ccs;
      const float* src = x + (((size_t)b * CC + ch) * HH + srow) * WW + half * 256 + lane * 4;
      __builtin_amdgcn_global_load_lds(
          (const __attribute__((address_space(1))) void*)src,
          (__attribute__((address_space(3))) void*)&lbx[bi][ccs * CHW_F + j * 512 + half * 256],
          16, 0, 0);
    }
  };

  f32x4 acc[4][2];
#pragma unroll
  for (int ot = 0; ot < 4; ++ot)
#pragma unroll
    for (int pt = 0; pt < 2; ++pt) acc[ot][pt] = (f32x4){0.f, 0.f, 0.f, 0.f};

  stage(0, 0);   // prologue prefetch

#pragma unroll 1
  for (int g = 0; g < NGRP; ++g) {
    const int bi = g & 1;

    // A fragments (r12-proven mapping + codegen: manual rne, wgt in L2).
    // Pinned BEFORE stage(g+1) so vmcnt(6) always drains them (oldest-first).
    short8 A[4];
    {
      const int lg = lane >> 4;
      const int c  = g * 2 + (lg >> 1);
#pragma unroll
      for (int ot = 0; ot < 4; ++ot) {
        const int o = ot * 16 + (lane & 15);
        const float* wp9 = wgt + ((size_t)o * 64 + c) * 9;
        short8 a;
        if ((lg & 1) == 0) {
#pragma unroll
          for (int j = 0; j < 8; ++j) a[j] = (short)(ushort)rne_bf16(wp9[j]);
        } else {
          a = (short8){0, 0, 0, 0, 0, 0, 0, 0};
          a[0] = (short)(ushort)rne_bf16(wp9[8]);
        }
        A[ot] = a;
      }
    }
    __builtin_amdgcn_sched_barrier(0);          // pin A-loads before stage(g+1)

    if (g < NGRP - 1) {
      stage(bi ^ 1, g + 1);                     // prefetch next group's windows
      asm volatile("s_waitcnt vmcnt(6)" ::: "memory");   // drain stage(g)+A; keep stage(g+1)
    } else {
      asm volatile("s_waitcnt vmcnt(0)" ::: "memory");
    }
    __builtin_amdgcn_sched_barrier(0);
    __builtin_amdgcn_s_barrier();               // BARRIER A: lbx[bi] visible everywhere
    __builtin_amdgcn_sched_barrier(0);

    // ---- gather channel 2g+cc for pixel p (r12 math, wave-local pixel set) ----
    {
      const float* Lc = &lbx[bi][cc * CHW_F];
      float s[KK];
#pragma unroll
      for (int k = 0; k < KK; ++k) {
        s[k] = fmaf(cw[k][3], Lc[jx[k][3]],
               fmaf(cw[k][2], Lc[jx[k][2]],
               fmaf(cw[k][1], Lc[jx[k][1]],
                    cw[k][0] * Lc[jx[k][0]])));
      }
      const uint b0 = rne_bf16(s[0]), b1 = rne_bf16(s[1]), b2 = rne_bf16(s[2]);
      const uint b3 = rne_bf16(s[3]), b4 = rne_bf16(s[4]), b5 = rne_bf16(s[5]);
      const uint b6 = rne_bf16(s[6]), b7 = rne_bf16(s[7]), b8 = rne_bf16(s[8]);
      uint2* Sr = (uint2*)(Sb + p * SSTR + cc * 16);
      Sr[0] = make_uint2(b0 | (b1 << 16), b2 | (b3 << 16));
      Sr[1] = make_uint2(b4 | (b5 << 16), b6 | (b7 << 16));
      Sb[p * SSTR + cc * 16 + 8] = (ushort)b8;
    }

    // NO BARRIER B: producer and consumer of these Sb rows are the same wave.
    asm volatile("s_waitcnt lgkmcnt(0)" ::: "memory");   // ds_writes landed
    __builtin_amdgcn_sched_barrier(0);

    // ---- B fragments + MFMA, scheduler-pinned (rule #18, r11/r12-proven) ----
    // lbx reuse safety: gather ds_reads drained at the lgkmcnt(0) above, which
    // precedes this wave's BARRIER A(g+1); stage(g+2) into this buffer is
    // issued only after BARRIER A(g+1) -> happens-before via barrier A.
    short8 Bfr[2];
#pragma unroll
    for (int pt = 0; pt < 2; ++pt) {
      const int prow = wid * 32 + pt * 16 + (lane & 15);
      Bfr[pt] = *(const short8*)(Sb + prow * SSTR + ((lane >> 4) & 3) * 8);
    }
    asm volatile("s_waitcnt lgkmcnt(0)" ::: "memory");
    __builtin_amdgcn_sched_barrier(0);          // MFMA must not hoist above the wait
#pragma unroll
    for (int ot = 0; ot < 4; ++ot)
#pragma unroll
      for (int pt = 0; pt < 2; ++pt)
        acc[ot][pt] = __builtin_amdgcn_mfma_f32_16x16x32_bf16(A[ot], Bfr[pt], acc[ot][pt], 0, 0, 0);
    __builtin_amdgcn_sched_barrier(0);          // nothing sinks/hoists across the cluster
  }

  // ---- epilogue: D row=(lane>>4)*4+r, col=lane&15 (m89 layout, proven) ----
#pragma unroll
  for (int ot = 0; ot < 4; ++ot) {
    const int o = ot * 16 + ((lane >> 4) & 3) * 4;
#pragma unroll
    for (int pt = 0; pt < 2; ++pt) {
      const int wcol = blockIdx.x * PXB + wid * 32 + pt * 16 + (lane & 15);
#pragma unroll
      for (int r = 0; r < 4; ++r)
        out[(((size_t)b * OO + (o + r)) * HH + h) * WW + wcol] = acc[ot][pt][r] + bias[o + r];
    }
  }
}

} // namespace

extern "C" void kernel_launch(void* const* d_in, const int* in_sizes, int n_in,
                              void* d_out, int out_size, void* d_ws, size_t ws_size,
                              hipStream_t stream) {
  const float* x      = (const float*)d_in[0];
  const float* weight = (const float*)d_in[1];
  const float* bias   = (const float*)d_in[2];
  float* out          = (float*)d_out;

  dim3 grid(WW / PXB, HH, BB);                  // 4 x 256 x 2
  hipLaunchKernelGGL(equiconv_mfma, grid, dim3(256), 0, stream,
                     x, weight, bias, out);
}